// Round 19
// baseline (520.873 us; speedup 1.0000x reference)
//
#include <hip/hip_runtime.h>

// B=16, C=128, H=256, W=64.  Pipeline:
//  K0: convert wq/wk/wv/wfc fp32->bf16 into ws tail (R8-validated)
//  K1: Q/K/V = relu(Wx+b) -> ws in SCRAMBLED (MFMA-D-native) layout:
//      u32 idx sidx(n,o2) gives lane-linear 512B wave stores. No WS
//      round-trip, ONE barrier (R18 lesson: keep block-shared XS + batched
//      MFMA so weight-load latency stays hidden; R17 lesson: barriers with
//      vmcnt(0) drains were the ~100us plateau).
//  K2: per-(b,w) attention (R16-validated compute); q/k/v READ SITES decode
//      the scrambled layout (2 uint2 loads per old short8). att stays w-major.
//  K3: out = relu(wfc . att^T + bfc) (R8-validated, reads w-major att)

typedef __attribute__((ext_vector_type(8))) short short8;
typedef __attribute__((ext_vector_type(4))) float f32x4;
typedef __attribute__((ext_vector_type(4))) int int4v;

#define MFMA16(acc, a, b) (acc) = __builtin_amdgcn_mfma_f32_16x16x32_bf16((a), (b), (acc), 0, 0, 0)

__device__ __forceinline__ unsigned short f2b(float f) {
  unsigned u = __builtin_bit_cast(unsigned, f);
  u = (u + 0x7fffu + ((u >> 16) & 1u)) >> 16;   // RNE
  return (unsigned short)u;
}

// Scrambled q/k/v layout: element (n 0..16383, o 0..127), o2 = o>>1 pair idx.
// u32 holds bf16 pair (o2*2, o2*2+1).  k1 lane (l16,g4,wvid,nt) writes uint2
// (o2 = wvid*8+g4*2, +1) at sidx(...) = base + 2*laneid -> coalesced.
__device__ __forceinline__ unsigned sidx(int n, int o2) {
  return ((unsigned)(((n >> 4) * 8 + (o2 >> 3)) * 64 + ((o2 >> 1) & 3) * 16 + (n & 15)) << 1)
         + (unsigned)(o2 & 1);
}

// [R][128c] bf16 tile, row-XOR swizzle (verified write-scalar/read-b128 pair)
__device__ __forceinline__ unsigned adr_s(int r, int c) {
  return (unsigned)(((r << 8) + (c << 1)) ^ ((r & 7) << 4));
}
// K1's XS [128j][128c]: stronger row-hash (rows written in stride-4 bursts)
__device__ __forceinline__ unsigned adr_q(int r, int c) {
  return (unsigned)(((r << 8) + (c << 1)) ^ (((r ^ (r >> 3)) & 7) << 4));
}
// V^T tile [128c][256g] (R5-verified double-XOR)
__device__ __forceinline__ unsigned adr_vt(int c, int g) {
  unsigned blk = (unsigned)(((g >> 3) ^ (c & 7) ^ ((c >> 3) & 7)) & 31);
  return (unsigned)((c << 9) + (blk << 4) + ((g & 7) << 1));
}
// per-wave P/att slice [16r][64c] bf16 (2KB), row-hash (R5-verified)
__device__ __forceinline__ unsigned ps_adr(int r, int c) {
  return (unsigned)(((r << 7) + (c << 1)) ^ (((r ^ (r >> 3)) & 7) << 4));
}

__device__ __forceinline__ short8 ldsf(const char* p, unsigned off) {
  return *(const short8*)(p + off);
}
// load one scrambled 8-c group (c = c16*8 .. +7) of row n -> short8
__device__ __forceinline__ short8 sld(const unsigned* base, int n, int c16) {
  uint2 ua = *(const uint2*)(base + sidx(n, c16 * 4));
  uint2 ub = *(const uint2*)(base + sidx(n, c16 * 4 + 2));
  int4v v = {(int)ua.x, (int)ua.y, (int)ub.x, (int)ub.y};
  return __builtin_bit_cast(short8, v);
}

// ================= K0: weight pre-convert fp32 -> bf16 =================
__global__ __launch_bounds__(256) void k0_wcvt(
    const float* __restrict__ wq, const float* __restrict__ wk,
    const float* __restrict__ wv, const float* __restrict__ wfc,
    unsigned short* __restrict__ wb)
{
  int i = blockIdx.x * 256 + threadIdx.x;    // 16384 float4's total
  int mat = i >> 12, off = (i & 4095) * 4;
  const float* src = (mat == 0) ? wq : (mat == 1) ? wk : (mat == 2) ? wv : wfc;
  float4 v = *(const float4*)(src + off);
  uint2 u;
  u.x = (unsigned)f2b(v.x) | ((unsigned)f2b(v.y) << 16);
  u.y = (unsigned)f2b(v.z) | ((unsigned)f2b(v.w) << 16);
  *(uint2*)(wb + mat * 16384 + off) = u;
}

// ================= K1: QKV projection, direct scrambled stores ==============
// grid = nbc*128; block tile = 128 n.  LDS: XS [128n][128c] (32K) only.
// ONE barrier. Stores: per (matrix, nt) one uint2/lane, wave-contiguous 512B.

__device__ __forceinline__ void k1_one(const unsigned short* wmat, const float* bias,
    unsigned* dst, const char* XS,
    int n0, int wvid, int l16, int g4) {
  const int strip = wvid * 16;
  short8 wf[4];
#pragma unroll
  for (int kk = 0; kk < 4; ++kk)
    wf[kk] = *(const short8*)(wmat + (strip + l16) * 128 + kk * 32 + g4 * 8);
  float4 b4 = *(const float4*)(bias + strip + g4 * 4);

#pragma unroll
  for (int nt = 0; nt < 8; ++nt) {
    f32x4 acc = {0.f, 0.f, 0.f, 0.f};
#pragma unroll
    for (int kk = 0; kk < 4; ++kk) {
      short8 xb = ldsf(XS, adr_q(nt * 16 + l16, kk * 32 + g4 * 8));
      MFMA16(acc, wf[kk], xb);   // D: col=l16 -> n', row=g4*4+r -> o
    }
    float y0 = fmaxf(acc[0] + b4.x, 0.f);
    float y1 = fmaxf(acc[1] + b4.y, 0.f);
    float y2 = fmaxf(acc[2] + b4.z, 0.f);
    float y3 = fmaxf(acc[3] + b4.w, 0.f);
    uint2 u;
    u.x = (unsigned)f2b(y0) | ((unsigned)f2b(y1) << 16);
    u.y = (unsigned)f2b(y2) | ((unsigned)f2b(y3) << 16);
    // o2 = wvid*8 + g4*2 (even) -> sidx = ((n>>4)*8+wvid)*128 + l*2, l=g4*16+l16
    *(uint2*)(dst + sidx(n0 + nt * 16 + l16, wvid * 8 + g4 * 2)) = u;
  }
}

__global__ __launch_bounds__(512, 4) void k1_qkv(
    const float* __restrict__ rep, const unsigned short* __restrict__ wb,
    const float* __restrict__ bq, const float* __restrict__ bk,
    const float* __restrict__ bv,
    unsigned* __restrict__ qo, unsigned* __restrict__ ko,
    unsigned* __restrict__ vo, int b0)
{
  extern __shared__ char smem[];
  char* XS = smem;   // 32K

  const int t = threadIdx.x;
  const int wvid = t >> 6, l = t & 63, l16 = l & 15, g4 = l >> 4;
  (void)l;
  const int brel = blockIdx.x >> 7;
  const int n0 = (blockIdx.x & 127) * 128;
  const int b = b0 + brel;
  const unsigned boff = (unsigned)brel * 1048576u;   // 1M u32 per b

  // stage X^T: rep[b][c][n0+j] -> XS[j][c]  (float4-coalesced reads)
#pragma unroll
  for (int it = 0; it < 8; ++it) {
    int i = it * 512 + t;
    int c = i >> 5, j4 = i & 31;
    float4 xv = *(const float4*)(rep + (size_t)(b * 128 + c) * 16384 + n0 + j4 * 4);
    float vv[4] = {xv.x, xv.y, xv.z, xv.w};
#pragma unroll
    for (int r = 0; r < 4; ++r)
      *(unsigned short*)(XS + adr_q(j4 * 4 + r, c)) = f2b(vv[r]);
  }
  __syncthreads();

  k1_one(wb,         bq, qo + boff, XS, n0, wvid, l16, g4);
  k1_one(wb + 16384, bk, ko + boff, XS, n0, wvid, l16, g4);
  k1_one(wb + 32768, bv, vo + boff, XS, n0, wvid, l16, g4);
}

// ================= K2: attention per (b,w), permuted-K, frag-reuse ==========
// R16-validated compute; q/k/v loads decode the scrambled layout via sld().
// 512 thr (8 waves), wave owns TWO 16-row m-tiles (hb0=wvid*32, hb1=+16).
// LDS: KS 64K @0, VTS 64K @64K, PS att-slices @128K (8 x 2K). Total 144K.

__global__ __launch_bounds__(512, 2) void k2_attn(
    const unsigned* __restrict__ qws, const unsigned* __restrict__ kws,
    const unsigned* __restrict__ vws, unsigned short* __restrict__ aws)
{
  extern __shared__ char smem[];
  char* KS  = smem;
  char* VTS = smem + (64 << 10);

  const int t = threadIdx.x;
  const int wvid = t >> 6, l = t & 63, l16 = l & 15, g4 = l >> 4;
  char* PS = smem + (128 << 10) + (wvid << 11);

  const int brel = blockIdx.x >> 6;
  const int w = blockIdx.x & 63;
  const unsigned boff = (unsigned)brel * 1048576u;
  const unsigned* qp = qws + boff;
  const unsigned* kp = kws + boff;
  const unsigned* vp = vws + boff;
  const size_t wbase = (size_t)(brel * 64 + w) * 256;   // att row of (b,w,h=0)

  const int hb0 = wvid * 32;
  const int hb1 = wvid * 32 + 16;

  // q rows for both m-tiles (scrambled decode; c-group c16 = kk*4+g4)
  short8 qa0[4], qa1[4];
#pragma unroll
  for (int kk = 0; kk < 4; ++kk) {
    qa0[kk] = sld(qp, (hb0 + l16) * 64 + w, kk * 4 + g4);
    qa1[kk] = sld(qp, (hb1 + l16) * 64 + w, kk * 4 + g4);
  }

  // stage K rows [g][c] at permuted position p(g)
#pragma unroll
  for (int it = 0; it < 8; ++it) {
    int i = it * 512 + t;
    int g = i >> 4, c16 = i & 15;
    int gp = (g & ~31) | ((g & 4) << 2) | ((g >> 1) & 12) | (g & 3);
    short8 kv = sld(kp, g * 64 + w, c16);
    *(short8*)(KS + adr_s(gp, c16 * 8)) = kv;
  }
  // stage V^T [c][g] (scalar swizzled writes, natural g)
#pragma unroll
  for (int it = 0; it < 8; ++it) {
    int i = it * 512 + t;
    int g = i >> 4, c16 = i & 15;
    short8 vv = sld(vp, g * 64 + w, c16);
#pragma unroll
    for (int j = 0; j < 8; ++j)
      *(unsigned short*)(VTS + adr_vt(c16 * 8 + j, g)) = (unsigned short)vv[j];
  }
  __syncthreads();

  const float SCL2 = 0.08838834764831845f * 1.4426950408889634f; // rsqrt(128)*log2e

  // swapped scores, frag-reuse: each kb read feeds both m-tiles
  f32x4 sc0[16], sc1[16];
#pragma unroll
  for (int gt = 0; gt < 16; ++gt) {
    f32x4 a0 = {0.f, 0.f, 0.f, 0.f};
    f32x4 a1 = {0.f, 0.f, 0.f, 0.f};
#pragma unroll
    for (int kk = 0; kk < 4; ++kk) {
      short8 kb = ldsf(KS, adr_s(gt * 16 + l16, kk * 32 + g4 * 8));
      MFMA16(a0, kb, qa0[kk]);
      MFMA16(a1, kb, qa1[kk]);
    }
    sc0[gt] = a0;
    sc1[gt] = a1;
  }

  // softmax m0 (row h = hb0+l16): in-lane + 2 shfl; pack to pk
  unsigned pk0a[16], pk1a[16];
  {
    float mm = fmaxf(fmaxf(sc0[0][0], sc0[0][1]), fmaxf(sc0[0][2], sc0[0][3]));
#pragma unroll
    for (int gt = 1; gt < 16; ++gt) {
      float m4 = fmaxf(fmaxf(sc0[gt][0], sc0[gt][1]), fmaxf(sc0[gt][2], sc0[gt][3]));
      mm = fmaxf(mm, m4);
    }
    mm = fmaxf(mm, __shfl_xor(mm, 16, 64));
    mm = fmaxf(mm, __shfl_xor(mm, 32, 64));
    const float mneg = -mm * SCL2;
    float s = 0.f;
#pragma unroll
    for (int gt = 0; gt < 16; ++gt) {
#pragma unroll
      for (int r = 0; r < 4; ++r) {
        float p = exp2f(fmaf(sc0[gt][r], SCL2, mneg));
        sc0[gt][r] = p;
        s += p;
      }
    }
    s += __shfl_xor(s, 16, 64);
    s += __shfl_xor(s, 32, 64);
    const float rcp = 1.0f / s;
#pragma unroll
    for (int gt = 0; gt < 16; ++gt) {
      pk0a[gt] = (unsigned)f2b(sc0[gt][0] * rcp) | ((unsigned)f2b(sc0[gt][1] * rcp) << 16);
      pk1a[gt] = (unsigned)f2b(sc0[gt][2] * rcp) | ((unsigned)f2b(sc0[gt][3] * rcp) << 16);
    }
  }
  // softmax m1
  unsigned pk0b[16], pk1b[16];
  {
    float mm = fmaxf(fmaxf(sc1[0][0], sc1[0][1]), fmaxf(sc1[0][2], sc1[0][3]));
#pragma unroll
    for (int gt = 1; gt < 16; ++gt) {
      float m4 = fmaxf(fmaxf(sc1[gt][0], sc1[gt][1]), fmaxf(sc1[gt][2], sc1[gt][3]));
      mm = fmaxf(mm, m4);
    }
    mm = fmaxf(mm, __shfl_xor(mm, 16, 64));
    mm = fmaxf(mm, __shfl_xor(mm, 32, 64));
    const float mneg = -mm * SCL2;
    float s = 0.f;
#pragma unroll
    for (int gt = 0; gt < 16; ++gt) {
#pragma unroll
      for (int r = 0; r < 4; ++r) {
        float p = exp2f(fmaf(sc1[gt][r], SCL2, mneg));
        sc1[gt][r] = p;
        s += p;
      }
    }
    s += __shfl_xor(s, 16, 64);
    s += __shfl_xor(s, 32, 64);
    const float rcp = 1.0f / s;
#pragma unroll
    for (int gt = 0; gt < 16; ++gt) {
      pk0b[gt] = (unsigned)f2b(sc1[gt][0] * rcp) | ((unsigned)f2b(sc1[gt][1] * rcp) << 16);
      pk1b[gt] = (unsigned)f2b(sc1[gt][2] * rcp) | ((unsigned)f2b(sc1[gt][3] * rcp) << 16);
    }
  }

  // PV, frag-reuse: each vb read feeds both m-tiles (lane-local A-frags)
  f32x4 oacc0[8], oacc1[8];
#pragma unroll
  for (int nt = 0; nt < 8; ++nt) {
    oacc0[nt] = (f32x4){0.f, 0.f, 0.f, 0.f};
    oacc1[nt] = (f32x4){0.f, 0.f, 0.f, 0.f};
  }
#pragma unroll
  for (int kks = 0; kks < 8; ++kks) {
    int4v pv0 = {(int)pk0a[2 * kks], (int)pk1a[2 * kks],
                 (int)pk0a[2 * kks + 1], (int)pk1a[2 * kks + 1]};
    int4v pv1 = {(int)pk0b[2 * kks], (int)pk1b[2 * kks],
                 (int)pk0b[2 * kks + 1], (int)pk1b[2 * kks + 1]};
    short8 pa0 = __builtin_bit_cast(short8, pv0);
    short8 pa1 = __builtin_bit_cast(short8, pv1);
#pragma unroll
    for (int nt = 0; nt < 8; ++nt) {
      short8 vb = ldsf(VTS, adr_vt(nt * 16 + l16, kks * 32 + g4 * 8));
      MFMA16(oacc0[nt], pa0, vb);
      MFMA16(oacc1[nt], pa1, vb);
    }
  }

  // att stores (normalized), R14-validated PS round-trip, once per m-tile
#pragma unroll
  for (int m = 0; m < 2; ++m) {
    const int hb = (m == 0) ? hb0 : hb1;
#pragma unroll
    for (int ch = 0; ch < 2; ++ch) {
#pragma unroll
      for (int nt4 = 0; nt4 < 4; ++nt4) {
        int nt = ch * 4 + nt4;
        f32x4 ov = (m == 0) ? oacc0[nt] : oacc1[nt];
#pragma unroll
        for (int r = 0; r < 4; ++r)
          *(unsigned short*)(PS + ps_adr(g4 * 4 + r, nt4 * 16 + l16)) = f2b(ov[r]);
      }
#pragma unroll
      for (int it = 0; it < 8; ++it) {
        int row = it * 2 + (l >> 5);   // 0..15
        int cd  = l & 31;              // dword within 128B row-half
        unsigned base = (unsigned)(row << 7) +
            (((unsigned)(cd << 2)) ^ (((unsigned)((row ^ (row >> 3)) & 7)) << 4));
        unsigned lo = *(const unsigned short*)(PS + base);
        unsigned hi = *(const unsigned short*)(PS + base + 2);
        ((unsigned*)aws)[(wbase + hb + row) * 64 + ch * 32 + cd] = lo | (hi << 16);
      }
    }
  }
}

// ================= K3: out = relu(wfc . att^T + bfc) — R8-validated ==========
// grid = nbc*64; block tile = 256 n.  LDS: AS [256n][128c] (64K).

__global__ __launch_bounds__(512, 4) void k3_conv(
    const unsigned short* __restrict__ aws, const unsigned short* __restrict__ wb,
    const float* __restrict__ bfc, float* __restrict__ out, int b0)
{
  extern __shared__ char smem[];
  char* AS = smem;

  const int t = threadIdx.x;
  const int wvid = t >> 6, l = t & 63, l16 = l & 15, g4 = l >> 4;
  (void)l;
  const int brel = blockIdx.x >> 6;
  const int n0 = (blockIdx.x & 63) * 256;
  const int b = b0 + brel;

#pragma unroll
  for (int it = 0; it < 8; ++it) {
    int i = it * 512 + t;
    int nn = i >> 4, c16 = i & 15;
    int n = n0 + nn;
    int h = n >> 6, w = n & 63;
    short8 av = *(const short8*)(aws + ((size_t)((brel * 64 + w) * 256 + h)) * 128 + c16 * 8);
    *(short8*)(AS + adr_s(nn, c16 * 8)) = av;
  }
  __syncthreads();

  const int strip = wvid * 16;
  const unsigned short* wfcb = wb + 3 * 16384;
  short8 wf[4];
#pragma unroll
  for (int kk = 0; kk < 4; ++kk)
    wf[kk] = *(const short8*)(wfcb + (strip + l16) * 128 + kk * 32 + g4 * 8);
  float bv4[4];
#pragma unroll
  for (int r = 0; r < 4; ++r) bv4[r] = bfc[strip + g4 * 4 + r];

#pragma unroll
  for (int nt = 0; nt < 16; ++nt) {
    f32x4 acc = {0.f, 0.f, 0.f, 0.f};
#pragma unroll
    for (int kk = 0; kk < 4; ++kk) {
      short8 ab = ldsf(AS, adr_s(nt * 16 + l16, kk * 32 + g4 * 8));
      MFMA16(acc, wf[kk], ab);
    }
#pragma unroll
    for (int r = 0; r < 4; ++r) {
      int o = strip + g4 * 4 + r;
      out[(size_t)(b * 128 + o) * 16384 + n0 + nt * 16 + l16] = fmaxf(acc[r] + bv4[r], 0.f);
    }
  }
}

extern "C" void kernel_launch(void* const* d_in, const int* in_sizes, int n_in,
                              void* d_out, int out_size, void* d_ws, size_t ws_size,
                              hipStream_t stream) {
  const float* rep = (const float*)d_in[0];
  const float* wq  = (const float*)d_in[1];
  const float* bq  = (const float*)d_in[2];
  const float* wk  = (const float*)d_in[3];
  const float* bk  = (const float*)d_in[4];
  const float* wv  = (const float*)d_in[5];
  const float* bv  = (const float*)d_in[6];
  const float* wfc = (const float*)d_in[7];
  const float* bfc = (const float*)d_in[8];
  float* out = (float*)d_out;
  (void)in_sizes; (void)n_in; (void)out_size;

  hipFuncSetAttribute((const void*)k1_qkv,  hipFuncAttributeMaxDynamicSharedMemorySize, 32 * 1024);
  hipFuncSetAttribute((const void*)k2_attn, hipFuncAttributeMaxDynamicSharedMemorySize, 144 * 1024);
  hipFuncSetAttribute((const void*)k3_conv, hipFuncAttributeMaxDynamicSharedMemorySize, 64 * 1024);

  const size_t wb_bytes = 4 * 16384 * 2;          // 128 KB bf16 weights
  const size_t per_b = (size_t)16384 * 128 * 2;   // 4 MiB per array per b
  if (ws_size < wb_bytes + 4 * per_b) return;     // needs >= ~16.1 MB
  size_t nb_max = (ws_size - wb_bytes) / (4 * per_b);
  int nb = (int)(nb_max < 16 ? nb_max : 16);

  char* ws = (char*)d_ws;
  unsigned* qws = (unsigned*)(ws);
  unsigned* kws = (unsigned*)(ws + (size_t)nb * per_b);
  unsigned* vws = (unsigned*)(ws + (size_t)nb * per_b * 2);
  unsigned short* aws = (unsigned short*)(ws + (size_t)nb * per_b * 3);
  unsigned short* wb  = (unsigned short*)(ws + (size_t)nb * per_b * 4);

  k0_wcvt<<<dim3(64), dim3(256), 0, stream>>>(wq, wk, wv, wfc, wb);

  for (int b0 = 0; b0 < 16; b0 += nb) {
    int nbc = (16 - b0) < nb ? (16 - b0) : nb;
    k1_qkv<<<dim3(nbc * 128), dim3(512), 32 * 1024, stream>>>(
        rep, wb, bq, bk, bv, qws, kws, vws, b0);
    k2_attn<<<dim3(nbc * 64), dim3(512), 144 * 1024, stream>>>(qws, kws, vws, aws);
    k3_conv<<<dim3(nbc * 64), dim3(512), 64 * 1024, stream>>>(aws, wb, bfc, out, b0);
  }
}

// Round 20
// 232.634 us; speedup vs baseline: 2.2390x; 2.2390x over previous
//
#include <hip/hip_runtime.h>

// B=16, C=128, H=256, W=64.  Pipeline (workspace W-MAJOR: [b][w][h][c]):
//  K0: convert wq/wk/wv/wfc fp32->bf16 into ws tail (R8-validated)
//  K1: Q/K/V = relu(Wx+b) -> ws bf16; 8KB quarter-staged rows (R17-validated)
//      + XCD-aware block swizzle (bijective remap only).
//  K2: per-(b,w) attention; permuted-K swapped QK^T, 8 waves x 2 m-tiles,
//      K/V fragment reuse (R16-validated, byte-identical)
//  K3: out = relu(wfc . att^T + bfc) (R8-validated) + XCD swizzle.

typedef __attribute__((ext_vector_type(8))) short short8;
typedef __attribute__((ext_vector_type(4))) float f32x4;
typedef __attribute__((ext_vector_type(4))) int int4v;

#define MFMA16(acc, a, b) (acc) = __builtin_amdgcn_mfma_f32_16x16x32_bf16((a), (b), (acc), 0, 0, 0)

__device__ __forceinline__ unsigned short f2b(float f) {
  unsigned u = __builtin_bit_cast(unsigned, f);
  u = (u + 0x7fffu + ((u >> 16) & 1u)) >> 16;   // RNE
  return (unsigned short)u;
}

// [R][128c] bf16 tile, row-XOR swizzle (verified write-scalar/read-b128 pair)
__device__ __forceinline__ unsigned adr_s(int r, int c) {
  return (unsigned)(((r << 8) + (c << 1)) ^ ((r & 7) << 4));
}
// K1's XS [128j][128c]: stronger row-hash (rows written in stride-4 bursts)
__device__ __forceinline__ unsigned adr_q(int r, int c) {
  return (unsigned)(((r << 8) + (c << 1)) ^ (((r ^ (r >> 3)) & 7) << 4));
}
// V^T tile [128c][256g] (R5-verified double-XOR)
__device__ __forceinline__ unsigned adr_vt(int c, int g) {
  unsigned blk = (unsigned)(((g >> 3) ^ (c & 7) ^ ((c >> 3) & 7)) & 31);
  return (unsigned)((c << 9) + (blk << 4) + ((g & 7) << 1));
}
// per-wave P/att slice [16r][64c] bf16 (2KB), row-hash (R5-verified)
__device__ __forceinline__ unsigned ps_adr(int r, int c) {
  return (unsigned)(((r << 7) + (c << 1)) ^ (((r ^ (r >> 3)) & 7) << 4));
}

__device__ __forceinline__ short8 ldsf(const char* p, unsigned off) {
  return *(const short8*)(p + off);
}

// ================= K0: weight pre-convert fp32 -> bf16 =================
__global__ __launch_bounds__(256) void k0_wcvt(
    const float* __restrict__ wq, const float* __restrict__ wk,
    const float* __restrict__ wv, const float* __restrict__ wfc,
    unsigned short* __restrict__ wb)
{
  int i = blockIdx.x * 256 + threadIdx.x;    // 16384 float4's total
  int mat = i >> 12, off = (i & 4095) * 4;
  const float* src = (mat == 0) ? wq : (mat == 1) ? wk : (mat == 2) ? wv : wfc;
  float4 v = *(const float4*)(src + off);
  uint2 u;
  u.x = (unsigned)f2b(v.x) | ((unsigned)f2b(v.y) << 16);
  u.y = (unsigned)f2b(v.z) | ((unsigned)f2b(v.w) << 16);
  *(uint2*)(wb + mat * 16384 + off) = u;
}

// ================= K1: QKV projection (R17-validated) + XCD swizzle ==========
// grid = nbc*128; block tile = 128 n (n = h*64+w).
// LDS: XS [128n][128c] @0 (32K), WS quarter-stage [32n][128c] @32K (8K). 40K.
// Output W-MAJOR: dst[((brel*64+w)*256 + h)*128 + c].

__device__ __forceinline__ void k1_one(const unsigned short* wmat, const float* bias,
    unsigned short* dst, const char* XS, char* WS,
    int brel, int n0, int wvid, int l, int l16, int g4) {
  const int strip = wvid * 16;
  short8 wf[4];
#pragma unroll
  for (int kk = 0; kk < 4; ++kk)
    wf[kk] = *(const short8*)(wmat + (strip + l16) * 128 + kk * 32 + g4 * 8);
  float bv4[4];
#pragma unroll
  for (int r = 0; r < 4; ++r) bv4[r] = bias[strip + g4 * 4 + r];

  f32x4 acc[8];
#pragma unroll
  for (int nt = 0; nt < 8; ++nt) acc[nt] = (f32x4){0.f, 0.f, 0.f, 0.f};
#pragma unroll
  for (int nt = 0; nt < 8; ++nt) {
#pragma unroll
    for (int kk = 0; kk < 4; ++kk) {
      short8 xb = ldsf(XS, adr_q(nt * 16 + l16, kk * 32 + g4 * 8));
      MFMA16(acc[nt], wf[kk], xb);   // D[o][n']: col=l16 -> n', row=g4*4+r -> o
    }
  }
  // four 32-row quarters through the 8K WS
#pragma unroll
  for (int qt = 0; qt < 4; ++qt) {
    __syncthreads();   // WS free (previous readback complete)
#pragma unroll
    for (int nt2 = 0; nt2 < 2; ++nt2) {
      int nt = qt * 2 + nt2;
      float y0 = fmaxf(acc[nt][0] + bv4[0], 0.f);
      float y1 = fmaxf(acc[nt][1] + bv4[1], 0.f);
      float y2 = fmaxf(acc[nt][2] + bv4[2], 0.f);
      float y3 = fmaxf(acc[nt][3] + bv4[3], 0.f);
      uint2 u;
      u.x = (unsigned)f2b(y0) | ((unsigned)f2b(y1) << 16);
      u.y = (unsigned)f2b(y2) | ((unsigned)f2b(y3) << 16);
      int row = nt2 * 16 + l16;                       // 0..31
      unsigned cb = (unsigned)(wvid * 32 + g4 * 8);
      *(uint2*)(WS + (unsigned)(row << 8) + (cb ^ ((unsigned)(row & 7) << 4))) = u;
    }
    __syncthreads();
    // readback full 256B rows -> w-major global rows
#pragma unroll
    for (int it = 0; it < 4; ++it) {
      int row = it * 8 + wvid;                        // 0..31
      unsigned u = *(const unsigned*)(WS + (unsigned)(row << 8) +
                                     (((unsigned)(l << 2)) ^ ((unsigned)(row & 7) << 4)));
      int n = n0 + qt * 32 + row;
      int h = n >> 6, w = n & 63;
      ((unsigned*)dst)[(size_t)((brel * 64 + w) * 256 + h) * 64 + l] = u;
    }
  }
}

__global__ __launch_bounds__(512, 4) void k1_qkv(
    const float* __restrict__ rep, const unsigned short* __restrict__ wb,
    const float* __restrict__ bq, const float* __restrict__ bk,
    const float* __restrict__ bv,
    unsigned short* __restrict__ qo, unsigned short* __restrict__ ko,
    unsigned short* __restrict__ vo, int b0, int nwg)
{
  extern __shared__ char smem[];
  char* XS = smem;               // 32K
  char* WS = smem + (32 << 10);  // 8K

  const int t = threadIdx.x;
  const int wvid = t >> 6, l = t & 63, l16 = l & 15, g4 = l >> 4;
  // XCD-aware bijective swizzle (nwg % 8 == 0 always: nbc*128)
  const int bid = (int)((blockIdx.x & 7) * (nwg >> 3) + (blockIdx.x >> 3));
  const int brel = bid >> 7;
  const int n0 = (bid & 127) * 128;
  const int b = b0 + brel;

#pragma unroll
  for (int it = 0; it < 8; ++it) {
    int i = it * 512 + t;
    int c = i >> 5, j4 = i & 31;
    float4 xv = *(const float4*)(rep + (size_t)(b * 128 + c) * 16384 + n0 + j4 * 4);
    float vv[4] = {xv.x, xv.y, xv.z, xv.w};
#pragma unroll
    for (int r = 0; r < 4; ++r)
      *(unsigned short*)(XS + adr_q(j4 * 4 + r, c)) = f2b(vv[r]);
  }
  __syncthreads();

  k1_one(wb,         bq, qo, XS, WS, brel, n0, wvid, l, l16, g4);
  k1_one(wb + 16384, bk, ko, XS, WS, brel, n0, wvid, l, l16, g4);
  k1_one(wb + 32768, bv, vo, XS, WS, brel, n0, wvid, l, l16, g4);
}

// ================= K2: attention per (b,w), permuted-K, frag-reuse ==========
// (R16-validated, byte-identical.)
// 512 thr (8 waves), wave owns TWO 16-row m-tiles (hb0=wvid*32, hb1=+16).
// LDS: KS 64K @0, VTS 64K @64K, PS att-slices @128K (8 x 2K). Total 144K.

__global__ __launch_bounds__(512, 2) void k2_attn(
    const unsigned short* __restrict__ qws, const unsigned short* __restrict__ kws,
    const unsigned short* __restrict__ vws, unsigned short* __restrict__ aws)
{
  extern __shared__ char smem[];
  char* KS  = smem;
  char* VTS = smem + (64 << 10);

  const int t = threadIdx.x;
  const int wvid = t >> 6, l = t & 63, l16 = l & 15, g4 = l >> 4;
  char* PS = smem + (128 << 10) + (wvid << 11);

  const int brel = blockIdx.x >> 6;
  const int w = blockIdx.x & 63;
  const size_t wbase = (size_t)((brel * 64 + w)) * 256;   // row index of (b,w,h=0)

  const int hb0 = wvid * 32;
  const int hb1 = wvid * 32 + 16;

  // q rows for both m-tiles (contiguous reads)
  short8 qa0[4], qa1[4];
#pragma unroll
  for (int kk = 0; kk < 4; ++kk) {
    qa0[kk] = *(const short8*)(qws + (wbase + hb0 + l16) * 128 + kk * 32 + g4 * 8);
    qa1[kk] = *(const short8*)(qws + (wbase + hb1 + l16) * 128 + kk * 32 + g4 * 8);
  }

  // stage K rows [g][c] at permuted position p(g) — contiguous global reads
#pragma unroll
  for (int it = 0; it < 8; ++it) {
    int i = it * 512 + t;
    int g = i >> 4, c16 = i & 15;
    int gp = (g & ~31) | ((g & 4) << 2) | ((g >> 1) & 12) | (g & 3);
    short8 kv = *(const short8*)(kws + (wbase + g) * 128 + c16 * 8);
    *(short8*)(KS + adr_s(gp, c16 * 8)) = kv;
  }
  // stage V^T [c][g] — contiguous reads, scalar swizzled writes (natural g)
#pragma unroll
  for (int it = 0; it < 8; ++it) {
    int i = it * 512 + t;
    int g = i >> 4, c16 = i & 15;
    short8 vv = *(const short8*)(vws + (wbase + g) * 128 + c16 * 8);
#pragma unroll
    for (int j = 0; j < 8; ++j)
      *(unsigned short*)(VTS + adr_vt(c16 * 8 + j, g)) = (unsigned short)vv[j];
  }
  __syncthreads();

  const float SCL2 = 0.08838834764831845f * 1.4426950408889634f; // rsqrt(128)*log2e

  // swapped scores, frag-reuse: each kb read feeds both m-tiles
  f32x4 sc0[16], sc1[16];
#pragma unroll
  for (int gt = 0; gt < 16; ++gt) {
    f32x4 a0 = {0.f, 0.f, 0.f, 0.f};
    f32x4 a1 = {0.f, 0.f, 0.f, 0.f};
#pragma unroll
    for (int kk = 0; kk < 4; ++kk) {
      short8 kb = ldsf(KS, adr_s(gt * 16 + l16, kk * 32 + g4 * 8));
      MFMA16(a0, kb, qa0[kk]);
      MFMA16(a1, kb, qa1[kk]);
    }
    sc0[gt] = a0;
    sc1[gt] = a1;
  }

  // softmax m0 (row h = hb0+l16): in-lane + 2 shfl; pack to pk (frees sc0)
  unsigned pk0a[16], pk1a[16];
  {
    float mm = fmaxf(fmaxf(sc0[0][0], sc0[0][1]), fmaxf(sc0[0][2], sc0[0][3]));
#pragma unroll
    for (int gt = 1; gt < 16; ++gt) {
      float m4 = fmaxf(fmaxf(sc0[gt][0], sc0[gt][1]), fmaxf(sc0[gt][2], sc0[gt][3]));
      mm = fmaxf(mm, m4);
    }
    mm = fmaxf(mm, __shfl_xor(mm, 16, 64));
    mm = fmaxf(mm, __shfl_xor(mm, 32, 64));
    const float mneg = -mm * SCL2;
    float s = 0.f;
#pragma unroll
    for (int gt = 0; gt < 16; ++gt) {
#pragma unroll
      for (int r = 0; r < 4; ++r) {
        float p = exp2f(fmaf(sc0[gt][r], SCL2, mneg));
        sc0[gt][r] = p;
        s += p;
      }
    }
    s += __shfl_xor(s, 16, 64);
    s += __shfl_xor(s, 32, 64);
    const float rcp = 1.0f / s;
#pragma unroll
    for (int gt = 0; gt < 16; ++gt) {
      pk0a[gt] = (unsigned)f2b(sc0[gt][0] * rcp) | ((unsigned)f2b(sc0[gt][1] * rcp) << 16);
      pk1a[gt] = (unsigned)f2b(sc0[gt][2] * rcp) | ((unsigned)f2b(sc0[gt][3] * rcp) << 16);
    }
  }
  // softmax m1
  unsigned pk0b[16], pk1b[16];
  {
    float mm = fmaxf(fmaxf(sc1[0][0], sc1[0][1]), fmaxf(sc1[0][2], sc1[0][3]));
#pragma unroll
    for (int gt = 1; gt < 16; ++gt) {
      float m4 = fmaxf(fmaxf(sc1[gt][0], sc1[gt][1]), fmaxf(sc1[gt][2], sc1[gt][3]));
      mm = fmaxf(mm, m4);
    }
    mm = fmaxf(mm, __shfl_xor(mm, 16, 64));
    mm = fmaxf(mm, __shfl_xor(mm, 32, 64));
    const float mneg = -mm * SCL2;
    float s = 0.f;
#pragma unroll
    for (int gt = 0; gt < 16; ++gt) {
#pragma unroll
      for (int r = 0; r < 4; ++r) {
        float p = exp2f(fmaf(sc1[gt][r], SCL2, mneg));
        sc1[gt][r] = p;
        s += p;
      }
    }
    s += __shfl_xor(s, 16, 64);
    s += __shfl_xor(s, 32, 64);
    const float rcp = 1.0f / s;
#pragma unroll
    for (int gt = 0; gt < 16; ++gt) {
      pk0b[gt] = (unsigned)f2b(sc1[gt][0] * rcp) | ((unsigned)f2b(sc1[gt][1] * rcp) << 16);
      pk1b[gt] = (unsigned)f2b(sc1[gt][2] * rcp) | ((unsigned)f2b(sc1[gt][3] * rcp) << 16);
    }
  }

  // PV, frag-reuse: each vb read feeds both m-tiles (lane-local A-frags)
  f32x4 oacc0[8], oacc1[8];
#pragma unroll
  for (int nt = 0; nt < 8; ++nt) {
    oacc0[nt] = (f32x4){0.f, 0.f, 0.f, 0.f};
    oacc1[nt] = (f32x4){0.f, 0.f, 0.f, 0.f};
  }
#pragma unroll
  for (int kks = 0; kks < 8; ++kks) {
    int4v pv0 = {(int)pk0a[2 * kks], (int)pk1a[2 * kks],
                 (int)pk0a[2 * kks + 1], (int)pk1a[2 * kks + 1]};
    int4v pv1 = {(int)pk0b[2 * kks], (int)pk1b[2 * kks],
                 (int)pk0b[2 * kks + 1], (int)pk1b[2 * kks + 1]};
    short8 pa0 = __builtin_bit_cast(short8, pv0);
    short8 pa1 = __builtin_bit_cast(short8, pv1);
#pragma unroll
    for (int nt = 0; nt < 8; ++nt) {
      short8 vb = ldsf(VTS, adr_vt(nt * 16 + l16, kks * 32 + g4 * 8));
      MFMA16(oacc0[nt], pa0, vb);
      MFMA16(oacc1[nt], pa1, vb);
    }
  }

  // att stores (normalized), R14-validated PS round-trip, once per m-tile
#pragma unroll
  for (int m = 0; m < 2; ++m) {
    const int hb = (m == 0) ? hb0 : hb1;
#pragma unroll
    for (int ch = 0; ch < 2; ++ch) {
#pragma unroll
      for (int nt4 = 0; nt4 < 4; ++nt4) {
        int nt = ch * 4 + nt4;
        f32x4 ov = (m == 0) ? oacc0[nt] : oacc1[nt];
#pragma unroll
        for (int r = 0; r < 4; ++r)
          *(unsigned short*)(PS + ps_adr(g4 * 4 + r, nt4 * 16 + l16)) = f2b(ov[r]);
      }
#pragma unroll
      for (int it = 0; it < 8; ++it) {
        int row = it * 2 + (l >> 5);   // 0..15
        int cd  = l & 31;              // dword within 128B row-half
        unsigned base = (unsigned)(row << 7) +
            (((unsigned)(cd << 2)) ^ (((unsigned)((row ^ (row >> 3)) & 7)) << 4));
        unsigned lo = *(const unsigned short*)(PS + base);
        unsigned hi = *(const unsigned short*)(PS + base + 2);
        ((unsigned*)aws)[(wbase + hb + row) * 64 + ch * 32 + cd] = lo | (hi << 16);
      }
    }
  }
}

// ================= K3: out = relu(wfc . att^T + bfc) + XCD swizzle ==========
// grid = nbc*64; block tile = 256 n.  LDS: AS [256n][128c] (64K).

__global__ __launch_bounds__(512, 4) void k3_conv(
    const unsigned short* __restrict__ aws, const unsigned short* __restrict__ wb,
    const float* __restrict__ bfc, float* __restrict__ out, int b0, int nwg)
{
  extern __shared__ char smem[];
  char* AS = smem;

  const int t = threadIdx.x;
  const int wvid = t >> 6, l = t & 63, l16 = l & 15, g4 = l >> 4;
  (void)l;
  const int bid = (int)((blockIdx.x & 7) * (nwg >> 3) + (blockIdx.x >> 3));
  const int brel = bid >> 6;
  const int n0 = (bid & 63) * 256;
  const int b = b0 + brel;

#pragma unroll
  for (int it = 0; it < 8; ++it) {
    int i = it * 512 + t;
    int nn = i >> 4, c16 = i & 15;
    int n = n0 + nn;
    int h = n >> 6, w = n & 63;
    short8 av = *(const short8*)(aws + ((size_t)((brel * 64 + w) * 256 + h)) * 128 + c16 * 8);
    *(short8*)(AS + adr_s(nn, c16 * 8)) = av;
  }
  __syncthreads();

  const int strip = wvid * 16;
  const unsigned short* wfcb = wb + 3 * 16384;
  short8 wf[4];
#pragma unroll
  for (int kk = 0; kk < 4; ++kk)
    wf[kk] = *(const short8*)(wfcb + (strip + l16) * 128 + kk * 32 + g4 * 8);
  float bv4[4];
#pragma unroll
  for (int r = 0; r < 4; ++r) bv4[r] = bfc[strip + g4 * 4 + r];

#pragma unroll
  for (int nt = 0; nt < 16; ++nt) {
    f32x4 acc = {0.f, 0.f, 0.f, 0.f};
#pragma unroll
    for (int kk = 0; kk < 4; ++kk) {
      short8 ab = ldsf(AS, adr_s(nt * 16 + l16, kk * 32 + g4 * 8));
      MFMA16(acc, wf[kk], ab);
    }
#pragma unroll
    for (int r = 0; r < 4; ++r) {
      int o = strip + g4 * 4 + r;
      out[(size_t)(b * 128 + o) * 16384 + n0 + nt * 16 + l16] = fmaxf(acc[r] + bv4[r], 0.f);
    }
  }
}

extern "C" void kernel_launch(void* const* d_in, const int* in_sizes, int n_in,
                              void* d_out, int out_size, void* d_ws, size_t ws_size,
                              hipStream_t stream) {
  const float* rep = (const float*)d_in[0];
  const float* wq  = (const float*)d_in[1];
  const float* bq  = (const float*)d_in[2];
  const float* wk  = (const float*)d_in[3];
  const float* bk  = (const float*)d_in[4];
  const float* wv  = (const float*)d_in[5];
  const float* bv  = (const float*)d_in[6];
  const float* wfc = (const float*)d_in[7];
  const float* bfc = (const float*)d_in[8];
  float* out = (float*)d_out;
  (void)in_sizes; (void)n_in; (void)out_size;

  hipFuncSetAttribute((const void*)k1_qkv,  hipFuncAttributeMaxDynamicSharedMemorySize, 40 * 1024);
  hipFuncSetAttribute((const void*)k2_attn, hipFuncAttributeMaxDynamicSharedMemorySize, 144 * 1024);
  hipFuncSetAttribute((const void*)k3_conv, hipFuncAttributeMaxDynamicSharedMemorySize, 64 * 1024);

  const size_t wb_bytes = 4 * 16384 * 2;          // 128 KB bf16 weights
  const size_t per_b = (size_t)16384 * 128 * 2;   // 4 MiB per array per b
  if (ws_size < wb_bytes + 4 * per_b) return;     // needs >= ~16.1 MB
  size_t nb_max = (ws_size - wb_bytes) / (4 * per_b);
  int nb = (int)(nb_max < 16 ? nb_max : 16);

  char* ws = (char*)d_ws;
  unsigned short* qws = (unsigned short*)(ws);
  unsigned short* kws = (unsigned short*)(ws + (size_t)nb * per_b);
  unsigned short* vws = (unsigned short*)(ws + (size_t)nb * per_b * 2);
  unsigned short* aws = (unsigned short*)(ws + (size_t)nb * per_b * 3);
  unsigned short* wb  = (unsigned short*)(ws + (size_t)nb * per_b * 4);

  k0_wcvt<<<dim3(64), dim3(256), 0, stream>>>(wq, wk, wv, wfc, wb);

  for (int b0 = 0; b0 < 16; b0 += nb) {
    int nbc = (16 - b0) < nb ? (16 - b0) : nb;
    k1_qkv<<<dim3(nbc * 128), dim3(512), 40 * 1024, stream>>>(
        rep, wb, bq, bk, bv, qws, kws, vws, b0, nbc * 128);
    k2_attn<<<dim3(nbc * 64), dim3(512), 144 * 1024, stream>>>(qws, kws, vws, aws);
    k3_conv<<<dim3(nbc * 64), dim3(512), 64 * 1024, stream>>>(aws, wb, bfc, out, b0, nbc * 64);
  }
}

// Round 21
// 230.134 us; speedup vs baseline: 2.2634x; 1.0109x over previous
//
#include <hip/hip_runtime.h>

// B=16, C=128, H=256, W=64.  Pipeline (workspace W-MAJOR: [b][w][h][c]):
//  K0: convert wq/wk/wv/wfc fp32->bf16 into ws tail (R8-validated)
//  K1: Q/K/V = relu(Wx+b) -> ws bf16; 8KB quarter-staged rows (R17-validated;
//      40KB LDS, 4 blocks/CU; default block order — XCD swizzle regressed).
//  K2: per-(b,w) attention; permuted-K swapped QK^T, 8 waves x 2 m-tiles,
//      K/V fragment reuse (R16-validated, byte-identical)
//  K3: out = relu(wfc . att^T + bfc) (R8-validated)

typedef __attribute__((ext_vector_type(8))) short short8;
typedef __attribute__((ext_vector_type(4))) float f32x4;
typedef __attribute__((ext_vector_type(4))) int int4v;

#define MFMA16(acc, a, b) (acc) = __builtin_amdgcn_mfma_f32_16x16x32_bf16((a), (b), (acc), 0, 0, 0)

__device__ __forceinline__ unsigned short f2b(float f) {
  unsigned u = __builtin_bit_cast(unsigned, f);
  u = (u + 0x7fffu + ((u >> 16) & 1u)) >> 16;   // RNE
  return (unsigned short)u;
}

// [R][128c] bf16 tile, row-XOR swizzle (verified write-scalar/read-b128 pair)
__device__ __forceinline__ unsigned adr_s(int r, int c) {
  return (unsigned)(((r << 8) + (c << 1)) ^ ((r & 7) << 4));
}
// K1's XS [128j][128c]: stronger row-hash (rows written in stride-4 bursts)
__device__ __forceinline__ unsigned adr_q(int r, int c) {
  return (unsigned)(((r << 8) + (c << 1)) ^ (((r ^ (r >> 3)) & 7) << 4));
}
// V^T tile [128c][256g] (R5-verified double-XOR)
__device__ __forceinline__ unsigned adr_vt(int c, int g) {
  unsigned blk = (unsigned)(((g >> 3) ^ (c & 7) ^ ((c >> 3) & 7)) & 31);
  return (unsigned)((c << 9) + (blk << 4) + ((g & 7) << 1));
}
// per-wave P/att slice [16r][64c] bf16 (2KB), row-hash (R5-verified)
__device__ __forceinline__ unsigned ps_adr(int r, int c) {
  return (unsigned)(((r << 7) + (c << 1)) ^ (((r ^ (r >> 3)) & 7) << 4));
}

__device__ __forceinline__ short8 ldsf(const char* p, unsigned off) {
  return *(const short8*)(p + off);
}

// ================= K0: weight pre-convert fp32 -> bf16 =================
__global__ __launch_bounds__(256) void k0_wcvt(
    const float* __restrict__ wq, const float* __restrict__ wk,
    const float* __restrict__ wv, const float* __restrict__ wfc,
    unsigned short* __restrict__ wb)
{
  int i = blockIdx.x * 256 + threadIdx.x;    // 16384 float4's total
  int mat = i >> 12, off = (i & 4095) * 4;
  const float* src = (mat == 0) ? wq : (mat == 1) ? wk : (mat == 2) ? wv : wfc;
  float4 v = *(const float4*)(src + off);
  uint2 u;
  u.x = (unsigned)f2b(v.x) | ((unsigned)f2b(v.y) << 16);
  u.y = (unsigned)f2b(v.z) | ((unsigned)f2b(v.w) << 16);
  *(uint2*)(wb + mat * 16384 + off) = u;
}

// ================= K1: QKV projection =================
// grid = nbc*128; block tile = 128 n (n = h*64+w).
// LDS: XS [128n][128c] @0 (32K), WS quarter-stage [32n][128c] @32K (8K). 40K.
// Output W-MAJOR: dst[((brel*64+w)*256 + h)*128 + c].

__device__ __forceinline__ void k1_one(const unsigned short* wmat, const float* bias,
    unsigned short* dst, const char* XS, char* WS,
    int brel, int n0, int wvid, int l, int l16, int g4) {
  const int strip = wvid * 16;
  short8 wf[4];
#pragma unroll
  for (int kk = 0; kk < 4; ++kk)
    wf[kk] = *(const short8*)(wmat + (strip + l16) * 128 + kk * 32 + g4 * 8);
  float bv4[4];
#pragma unroll
  for (int r = 0; r < 4; ++r) bv4[r] = bias[strip + g4 * 4 + r];

  f32x4 acc[8];
#pragma unroll
  for (int nt = 0; nt < 8; ++nt) acc[nt] = (f32x4){0.f, 0.f, 0.f, 0.f};
#pragma unroll
  for (int nt = 0; nt < 8; ++nt) {
#pragma unroll
    for (int kk = 0; kk < 4; ++kk) {
      short8 xb = ldsf(XS, adr_q(nt * 16 + l16, kk * 32 + g4 * 8));
      MFMA16(acc[nt], wf[kk], xb);   // D[o][n']: col=l16 -> n', row=g4*4+r -> o
    }
  }
  // four 32-row quarters through the 8K WS
#pragma unroll
  for (int qt = 0; qt < 4; ++qt) {
    __syncthreads();   // WS free (previous readback complete)
#pragma unroll
    for (int nt2 = 0; nt2 < 2; ++nt2) {
      int nt = qt * 2 + nt2;
      float y0 = fmaxf(acc[nt][0] + bv4[0], 0.f);
      float y1 = fmaxf(acc[nt][1] + bv4[1], 0.f);
      float y2 = fmaxf(acc[nt][2] + bv4[2], 0.f);
      float y3 = fmaxf(acc[nt][3] + bv4[3], 0.f);
      uint2 u;
      u.x = (unsigned)f2b(y0) | ((unsigned)f2b(y1) << 16);
      u.y = (unsigned)f2b(y2) | ((unsigned)f2b(y3) << 16);
      int row = nt2 * 16 + l16;                       // 0..31
      unsigned cb = (unsigned)(wvid * 32 + g4 * 8);
      *(uint2*)(WS + (unsigned)(row << 8) + (cb ^ ((unsigned)(row & 7) << 4))) = u;
    }
    __syncthreads();
    // readback full 256B rows -> w-major global rows
#pragma unroll
    for (int it = 0; it < 4; ++it) {
      int row = it * 8 + wvid;                        // 0..31
      unsigned u = *(const unsigned*)(WS + (unsigned)(row << 8) +
                                     (((unsigned)(l << 2)) ^ ((unsigned)(row & 7) << 4)));
      int n = n0 + qt * 32 + row;
      int h = n >> 6, w = n & 63;
      ((unsigned*)dst)[(size_t)((brel * 64 + w) * 256 + h) * 64 + l] = u;
    }
  }
}

__global__ __launch_bounds__(512, 4) void k1_qkv(
    const float* __restrict__ rep, const unsigned short* __restrict__ wb,
    const float* __restrict__ bq, const float* __restrict__ bk,
    const float* __restrict__ bv,
    unsigned short* __restrict__ qo, unsigned short* __restrict__ ko,
    unsigned short* __restrict__ vo, int b0)
{
  extern __shared__ char smem[];
  char* XS = smem;               // 32K
  char* WS = smem + (32 << 10);  // 8K

  const int t = threadIdx.x;
  const int wvid = t >> 6, l = t & 63, l16 = l & 15, g4 = l >> 4;
  const int brel = blockIdx.x >> 7;
  const int n0 = (blockIdx.x & 127) * 128;
  const int b = b0 + brel;

#pragma unroll
  for (int it = 0; it < 8; ++it) {
    int i = it * 512 + t;
    int c = i >> 5, j4 = i & 31;
    float4 xv = *(const float4*)(rep + (size_t)(b * 128 + c) * 16384 + n0 + j4 * 4);
    float vv[4] = {xv.x, xv.y, xv.z, xv.w};
#pragma unroll
    for (int r = 0; r < 4; ++r)
      *(unsigned short*)(XS + adr_q(j4 * 4 + r, c)) = f2b(vv[r]);
  }
  __syncthreads();

  k1_one(wb,         bq, qo, XS, WS, brel, n0, wvid, l, l16, g4);
  k1_one(wb + 16384, bk, ko, XS, WS, brel, n0, wvid, l, l16, g4);
  k1_one(wb + 32768, bv, vo, XS, WS, brel, n0, wvid, l, l16, g4);
}

// ================= K2: attention per (b,w), permuted-K, frag-reuse ==========
// (R16-validated, byte-identical.)
// 512 thr (8 waves), wave owns TWO 16-row m-tiles (hb0=wvid*32, hb1=+16).
// LDS: KS 64K @0, VTS 64K @64K, PS att-slices @128K (8 x 2K). Total 144K.

__global__ __launch_bounds__(512, 2) void k2_attn(
    const unsigned short* __restrict__ qws, const unsigned short* __restrict__ kws,
    const unsigned short* __restrict__ vws, unsigned short* __restrict__ aws)
{
  extern __shared__ char smem[];
  char* KS  = smem;
  char* VTS = smem + (64 << 10);

  const int t = threadIdx.x;
  const int wvid = t >> 6, l = t & 63, l16 = l & 15, g4 = l >> 4;
  char* PS = smem + (128 << 10) + (wvid << 11);

  const int brel = blockIdx.x >> 6;
  const int w = blockIdx.x & 63;
  const size_t wbase = (size_t)((brel * 64 + w)) * 256;   // row index of (b,w,h=0)

  const int hb0 = wvid * 32;
  const int hb1 = wvid * 32 + 16;

  // q rows for both m-tiles (contiguous reads)
  short8 qa0[4], qa1[4];
#pragma unroll
  for (int kk = 0; kk < 4; ++kk) {
    qa0[kk] = *(const short8*)(qws + (wbase + hb0 + l16) * 128 + kk * 32 + g4 * 8);
    qa1[kk] = *(const short8*)(qws + (wbase + hb1 + l16) * 128 + kk * 32 + g4 * 8);
  }

  // stage K rows [g][c] at permuted position p(g) — contiguous global reads
#pragma unroll
  for (int it = 0; it < 8; ++it) {
    int i = it * 512 + t;
    int g = i >> 4, c16 = i & 15;
    int gp = (g & ~31) | ((g & 4) << 2) | ((g >> 1) & 12) | (g & 3);
    short8 kv = *(const short8*)(kws + (wbase + g) * 128 + c16 * 8);
    *(short8*)(KS + adr_s(gp, c16 * 8)) = kv;
  }
  // stage V^T [c][g] — contiguous reads, scalar swizzled writes (natural g)
#pragma unroll
  for (int it = 0; it < 8; ++it) {
    int i = it * 512 + t;
    int g = i >> 4, c16 = i & 15;
    short8 vv = *(const short8*)(vws + (wbase + g) * 128 + c16 * 8);
#pragma unroll
    for (int j = 0; j < 8; ++j)
      *(unsigned short*)(VTS + adr_vt(c16 * 8 + j, g)) = (unsigned short)vv[j];
  }
  __syncthreads();

  const float SCL2 = 0.08838834764831845f * 1.4426950408889634f; // rsqrt(128)*log2e

  // swapped scores, frag-reuse: each kb read feeds both m-tiles
  f32x4 sc0[16], sc1[16];
#pragma unroll
  for (int gt = 0; gt < 16; ++gt) {
    f32x4 a0 = {0.f, 0.f, 0.f, 0.f};
    f32x4 a1 = {0.f, 0.f, 0.f, 0.f};
#pragma unroll
    for (int kk = 0; kk < 4; ++kk) {
      short8 kb = ldsf(KS, adr_s(gt * 16 + l16, kk * 32 + g4 * 8));
      MFMA16(a0, kb, qa0[kk]);
      MFMA16(a1, kb, qa1[kk]);
    }
    sc0[gt] = a0;
    sc1[gt] = a1;
  }

  // softmax m0 (row h = hb0+l16): in-lane + 2 shfl; pack to pk (frees sc0)
  unsigned pk0a[16], pk1a[16];
  {
    float mm = fmaxf(fmaxf(sc0[0][0], sc0[0][1]), fmaxf(sc0[0][2], sc0[0][3]));
#pragma unroll
    for (int gt = 1; gt < 16; ++gt) {
      float m4 = fmaxf(fmaxf(sc0[gt][0], sc0[gt][1]), fmaxf(sc0[gt][2], sc0[gt][3]));
      mm = fmaxf(mm, m4);
    }
    mm = fmaxf(mm, __shfl_xor(mm, 16, 64));
    mm = fmaxf(mm, __shfl_xor(mm, 32, 64));
    const float mneg = -mm * SCL2;
    float s = 0.f;
#pragma unroll
    for (int gt = 0; gt < 16; ++gt) {
#pragma unroll
      for (int r = 0; r < 4; ++r) {
        float p = exp2f(fmaf(sc0[gt][r], SCL2, mneg));
        sc0[gt][r] = p;
        s += p;
      }
    }
    s += __shfl_xor(s, 16, 64);
    s += __shfl_xor(s, 32, 64);
    const float rcp = 1.0f / s;
#pragma unroll
    for (int gt = 0; gt < 16; ++gt) {
      pk0a[gt] = (unsigned)f2b(sc0[gt][0] * rcp) | ((unsigned)f2b(sc0[gt][1] * rcp) << 16);
      pk1a[gt] = (unsigned)f2b(sc0[gt][2] * rcp) | ((unsigned)f2b(sc0[gt][3] * rcp) << 16);
    }
  }
  // softmax m1
  unsigned pk0b[16], pk1b[16];
  {
    float mm = fmaxf(fmaxf(sc1[0][0], sc1[0][1]), fmaxf(sc1[0][2], sc1[0][3]));
#pragma unroll
    for (int gt = 1; gt < 16; ++gt) {
      float m4 = fmaxf(fmaxf(sc1[gt][0], sc1[gt][1]), fmaxf(sc1[gt][2], sc1[gt][3]));
      mm = fmaxf(mm, m4);
    }
    mm = fmaxf(mm, __shfl_xor(mm, 16, 64));
    mm = fmaxf(mm, __shfl_xor(mm, 32, 64));
    const float mneg = -mm * SCL2;
    float s = 0.f;
#pragma unroll
    for (int gt = 0; gt < 16; ++gt) {
#pragma unroll
      for (int r = 0; r < 4; ++r) {
        float p = exp2f(fmaf(sc1[gt][r], SCL2, mneg));
        sc1[gt][r] = p;
        s += p;
      }
    }
    s += __shfl_xor(s, 16, 64);
    s += __shfl_xor(s, 32, 64);
    const float rcp = 1.0f / s;
#pragma unroll
    for (int gt = 0; gt < 16; ++gt) {
      pk0b[gt] = (unsigned)f2b(sc1[gt][0] * rcp) | ((unsigned)f2b(sc1[gt][1] * rcp) << 16);
      pk1b[gt] = (unsigned)f2b(sc1[gt][2] * rcp) | ((unsigned)f2b(sc1[gt][3] * rcp) << 16);
    }
  }

  // PV, frag-reuse: each vb read feeds both m-tiles (lane-local A-frags)
  f32x4 oacc0[8], oacc1[8];
#pragma unroll
  for (int nt = 0; nt < 8; ++nt) {
    oacc0[nt] = (f32x4){0.f, 0.f, 0.f, 0.f};
    oacc1[nt] = (f32x4){0.f, 0.f, 0.f, 0.f};
  }
#pragma unroll
  for (int kks = 0; kks < 8; ++kks) {
    int4v pv0 = {(int)pk0a[2 * kks], (int)pk1a[2 * kks],
                 (int)pk0a[2 * kks + 1], (int)pk1a[2 * kks + 1]};
    int4v pv1 = {(int)pk0b[2 * kks], (int)pk1b[2 * kks],
                 (int)pk0b[2 * kks + 1], (int)pk1b[2 * kks + 1]};
    short8 pa0 = __builtin_bit_cast(short8, pv0);
    short8 pa1 = __builtin_bit_cast(short8, pv1);
#pragma unroll
    for (int nt = 0; nt < 8; ++nt) {
      short8 vb = ldsf(VTS, adr_vt(nt * 16 + l16, kks * 32 + g4 * 8));
      MFMA16(oacc0[nt], pa0, vb);
      MFMA16(oacc1[nt], pa1, vb);
    }
  }

  // att stores (normalized), R14-validated PS round-trip, once per m-tile
#pragma unroll
  for (int m = 0; m < 2; ++m) {
    const int hb = (m == 0) ? hb0 : hb1;
#pragma unroll
    for (int ch = 0; ch < 2; ++ch) {
#pragma unroll
      for (int nt4 = 0; nt4 < 4; ++nt4) {
        int nt = ch * 4 + nt4;
        f32x4 ov = (m == 0) ? oacc0[nt] : oacc1[nt];
#pragma unroll
        for (int r = 0; r < 4; ++r)
          *(unsigned short*)(PS + ps_adr(g4 * 4 + r, nt4 * 16 + l16)) = f2b(ov[r]);
      }
#pragma unroll
      for (int it = 0; it < 8; ++it) {
        int row = it * 2 + (l >> 5);   // 0..15
        int cd  = l & 31;              // dword within 128B row-half
        unsigned base = (unsigned)(row << 7) +
            (((unsigned)(cd << 2)) ^ (((unsigned)((row ^ (row >> 3)) & 7)) << 4));
        unsigned lo = *(const unsigned short*)(PS + base);
        unsigned hi = *(const unsigned short*)(PS + base + 2);
        ((unsigned*)aws)[(wbase + hb + row) * 64 + ch * 32 + cd] = lo | (hi << 16);
      }
    }
  }
}

// ================= K3: out = relu(wfc . att^T + bfc) — R8-validated ==========
// grid = nbc*64; block tile = 256 n.  LDS: AS [256n][128c] (64K).

__global__ __launch_bounds__(512, 4) void k3_conv(
    const unsigned short* __restrict__ aws, const unsigned short* __restrict__ wb,
    const float* __restrict__ bfc, float* __restrict__ out, int b0)
{
  extern __shared__ char smem[];
  char* AS = smem;

  const int t = threadIdx.x;
  const int wvid = t >> 6, l = t & 63, l16 = l & 15, g4 = l >> 4;
  (void)l;
  const int brel = blockIdx.x >> 6;
  const int n0 = (blockIdx.x & 63) * 256;
  const int b = b0 + brel;

#pragma unroll
  for (int it = 0; it < 8; ++it) {
    int i = it * 512 + t;
    int nn = i >> 4, c16 = i & 15;
    int n = n0 + nn;
    int h = n >> 6, w = n & 63;
    short8 av = *(const short8*)(aws + ((size_t)((brel * 64 + w) * 256 + h)) * 128 + c16 * 8);
    *(short8*)(AS + adr_s(nn, c16 * 8)) = av;
  }
  __syncthreads();

  const int strip = wvid * 16;
  const unsigned short* wfcb = wb + 3 * 16384;
  short8 wf[4];
#pragma unroll
  for (int kk = 0; kk < 4; ++kk)
    wf[kk] = *(const short8*)(wfcb + (strip + l16) * 128 + kk * 32 + g4 * 8);
  float bv4[4];
#pragma unroll
  for (int r = 0; r < 4; ++r) bv4[r] = bfc[strip + g4 * 4 + r];

#pragma unroll
  for (int nt = 0; nt < 16; ++nt) {
    f32x4 acc = {0.f, 0.f, 0.f, 0.f};
#pragma unroll
    for (int kk = 0; kk < 4; ++kk) {
      short8 ab = ldsf(AS, adr_s(nt * 16 + l16, kk * 32 + g4 * 8));
      MFMA16(acc, wf[kk], ab);
    }
#pragma unroll
    for (int r = 0; r < 4; ++r) {
      int o = strip + g4 * 4 + r;
      out[(size_t)(b * 128 + o) * 16384 + n0 + nt * 16 + l16] = fmaxf(acc[r] + bv4[r], 0.f);
    }
  }
}

extern "C" void kernel_launch(void* const* d_in, const int* in_sizes, int n_in,
                              void* d_out, int out_size, void* d_ws, size_t ws_size,
                              hipStream_t stream) {
  const float* rep = (const float*)d_in[0];
  const float* wq  = (const float*)d_in[1];
  const float* bq  = (const float*)d_in[2];
  const float* wk  = (const float*)d_in[3];
  const float* bk  = (const float*)d_in[4];
  const float* wv  = (const float*)d_in[5];
  const float* bv  = (const float*)d_in[6];
  const float* wfc = (const float*)d_in[7];
  const float* bfc = (const float*)d_in[8];
  float* out = (float*)d_out;
  (void)in_sizes; (void)n_in; (void)out_size;

  hipFuncSetAttribute((const void*)k1_qkv,  hipFuncAttributeMaxDynamicSharedMemorySize, 40 * 1024);
  hipFuncSetAttribute((const void*)k2_attn, hipFuncAttributeMaxDynamicSharedMemorySize, 144 * 1024);
  hipFuncSetAttribute((const void*)k3_conv, hipFuncAttributeMaxDynamicSharedMemorySize, 64 * 1024);

  const size_t wb_bytes = 4 * 16384 * 2;          // 128 KB bf16 weights
  const size_t per_b = (size_t)16384 * 128 * 2;   // 4 MiB per array per b
  if (ws_size < wb_bytes + 4 * per_b) return;     // needs >= ~16.1 MB
  size_t nb_max = (ws_size - wb_bytes) / (4 * per_b);
  int nb = (int)(nb_max < 16 ? nb_max : 16);

  char* ws = (char*)d_ws;
  unsigned short* qws = (unsigned short*)(ws);
  unsigned short* kws = (unsigned short*)(ws + (size_t)nb * per_b);
  unsigned short* vws = (unsigned short*)(ws + (size_t)nb * per_b * 2);
  unsigned short* aws = (unsigned short*)(ws + (size_t)nb * per_b * 3);
  unsigned short* wb  = (unsigned short*)(ws + (size_t)nb * per_b * 4);

  k0_wcvt<<<dim3(64), dim3(256), 0, stream>>>(wq, wk, wv, wfc, wb);

  for (int b0 = 0; b0 < 16; b0 += nb) {
    int nbc = (16 - b0) < nb ? (16 - b0) : nb;
    k1_qkv<<<dim3(nbc * 128), dim3(512), 40 * 1024, stream>>>(
        rep, wb, bq, bk, bv, qws, kws, vws, b0);
    k2_attn<<<dim3(nbc * 64), dim3(512), 144 * 1024, stream>>>(qws, kws, vws, aws);
    k3_conv<<<dim3(nbc * 64), dim3(512), 64 * 1024, stream>>>(aws, wb, bfc, out, b0);
  }
}

// Round 22
// 227.424 us; speedup vs baseline: 2.2903x; 1.0119x over previous
//
#include <hip/hip_runtime.h>

// B=16, C=128, H=256, W=64.  Pipeline (workspace W-MAJOR: [b][w][h][c]):
//  K0: convert wq/wk/wv/wfc fp32->bf16 into ws tail (R8-validated)
//  K1: Q/K/V = relu(Wx+b) -> ws bf16; 8KB quarter-staged rows (R17/R21-validated)
//  K2: per-(b,w) attention; R16-validated compute (permuted-K swapped QK^T,
//      8 waves x 2 m-tiles, frag-reuse) with TIME-MULTIPLEXED 64K S buffer
//      (K for QK, then V^T for PV — R8-validated schedule): LDS 144K -> 80K
//      => 2 blocks/CU (was 1).
//  K3: out = relu(wfc . att^T + bfc) (R8-validated)

typedef __attribute__((ext_vector_type(8))) short short8;
typedef __attribute__((ext_vector_type(4))) float f32x4;
typedef __attribute__((ext_vector_type(4))) int int4v;

#define MFMA16(acc, a, b) (acc) = __builtin_amdgcn_mfma_f32_16x16x32_bf16((a), (b), (acc), 0, 0, 0)

__device__ __forceinline__ unsigned short f2b(float f) {
  unsigned u = __builtin_bit_cast(unsigned, f);
  u = (u + 0x7fffu + ((u >> 16) & 1u)) >> 16;   // RNE
  return (unsigned short)u;
}

// [R][128c] bf16 tile, row-XOR swizzle (verified write-scalar/read-b128 pair)
__device__ __forceinline__ unsigned adr_s(int r, int c) {
  return (unsigned)(((r << 8) + (c << 1)) ^ ((r & 7) << 4));
}
// K1's XS [128j][128c]: stronger row-hash (rows written in stride-4 bursts)
__device__ __forceinline__ unsigned adr_q(int r, int c) {
  return (unsigned)(((r << 8) + (c << 1)) ^ (((r ^ (r >> 3)) & 7) << 4));
}
// V^T tile [128c][256g] (R5-verified double-XOR)
__device__ __forceinline__ unsigned adr_vt(int c, int g) {
  unsigned blk = (unsigned)(((g >> 3) ^ (c & 7) ^ ((c >> 3) & 7)) & 31);
  return (unsigned)((c << 9) + (blk << 4) + ((g & 7) << 1));
}
// per-wave P/att slice [16r][64c] bf16 (2KB), row-hash (R5-verified)
__device__ __forceinline__ unsigned ps_adr(int r, int c) {
  return (unsigned)(((r << 7) + (c << 1)) ^ (((r ^ (r >> 3)) & 7) << 4));
}

__device__ __forceinline__ short8 ldsf(const char* p, unsigned off) {
  return *(const short8*)(p + off);
}

// ================= K0: weight pre-convert fp32 -> bf16 =================
__global__ __launch_bounds__(256) void k0_wcvt(
    const float* __restrict__ wq, const float* __restrict__ wk,
    const float* __restrict__ wv, const float* __restrict__ wfc,
    unsigned short* __restrict__ wb)
{
  int i = blockIdx.x * 256 + threadIdx.x;    // 16384 float4's total
  int mat = i >> 12, off = (i & 4095) * 4;
  const float* src = (mat == 0) ? wq : (mat == 1) ? wk : (mat == 2) ? wv : wfc;
  float4 v = *(const float4*)(src + off);
  uint2 u;
  u.x = (unsigned)f2b(v.x) | ((unsigned)f2b(v.y) << 16);
  u.y = (unsigned)f2b(v.z) | ((unsigned)f2b(v.w) << 16);
  *(uint2*)(wb + mat * 16384 + off) = u;
}

// ================= K1: QKV projection (R21-validated, byte-identical) ========
// grid = nbc*128; block tile = 128 n (n = h*64+w).
// LDS: XS [128n][128c] @0 (32K), WS quarter-stage [32n][128c] @32K (8K). 40K.
// Output W-MAJOR: dst[((brel*64+w)*256 + h)*128 + c].

__device__ __forceinline__ void k1_one(const unsigned short* wmat, const float* bias,
    unsigned short* dst, const char* XS, char* WS,
    int brel, int n0, int wvid, int l, int l16, int g4) {
  const int strip = wvid * 16;
  short8 wf[4];
#pragma unroll
  for (int kk = 0; kk < 4; ++kk)
    wf[kk] = *(const short8*)(wmat + (strip + l16) * 128 + kk * 32 + g4 * 8);
  float bv4[4];
#pragma unroll
  for (int r = 0; r < 4; ++r) bv4[r] = bias[strip + g4 * 4 + r];

  f32x4 acc[8];
#pragma unroll
  for (int nt = 0; nt < 8; ++nt) acc[nt] = (f32x4){0.f, 0.f, 0.f, 0.f};
#pragma unroll
  for (int nt = 0; nt < 8; ++nt) {
#pragma unroll
    for (int kk = 0; kk < 4; ++kk) {
      short8 xb = ldsf(XS, adr_q(nt * 16 + l16, kk * 32 + g4 * 8));
      MFMA16(acc[nt], wf[kk], xb);   // D[o][n']: col=l16 -> n', row=g4*4+r -> o
    }
  }
  // four 32-row quarters through the 8K WS
#pragma unroll
  for (int qt = 0; qt < 4; ++qt) {
    __syncthreads();   // WS free (previous readback complete)
#pragma unroll
    for (int nt2 = 0; nt2 < 2; ++nt2) {
      int nt = qt * 2 + nt2;
      float y0 = fmaxf(acc[nt][0] + bv4[0], 0.f);
      float y1 = fmaxf(acc[nt][1] + bv4[1], 0.f);
      float y2 = fmaxf(acc[nt][2] + bv4[2], 0.f);
      float y3 = fmaxf(acc[nt][3] + bv4[3], 0.f);
      uint2 u;
      u.x = (unsigned)f2b(y0) | ((unsigned)f2b(y1) << 16);
      u.y = (unsigned)f2b(y2) | ((unsigned)f2b(y3) << 16);
      int row = nt2 * 16 + l16;                       // 0..31
      unsigned cb = (unsigned)(wvid * 32 + g4 * 8);
      *(uint2*)(WS + (unsigned)(row << 8) + (cb ^ ((unsigned)(row & 7) << 4))) = u;
    }
    __syncthreads();
    // readback full 256B rows -> w-major global rows
#pragma unroll
    for (int it = 0; it < 4; ++it) {
      int row = it * 8 + wvid;                        // 0..31
      unsigned u = *(const unsigned*)(WS + (unsigned)(row << 8) +
                                     (((unsigned)(l << 2)) ^ ((unsigned)(row & 7) << 4)));
      int n = n0 + qt * 32 + row;
      int h = n >> 6, w = n & 63;
      ((unsigned*)dst)[(size_t)((brel * 64 + w) * 256 + h) * 64 + l] = u;
    }
  }
}

__global__ __launch_bounds__(512, 4) void k1_qkv(
    const float* __restrict__ rep, const unsigned short* __restrict__ wb,
    const float* __restrict__ bq, const float* __restrict__ bk,
    const float* __restrict__ bv,
    unsigned short* __restrict__ qo, unsigned short* __restrict__ ko,
    unsigned short* __restrict__ vo, int b0)
{
  extern __shared__ char smem[];
  char* XS = smem;               // 32K
  char* WS = smem + (32 << 10);  // 8K

  const int t = threadIdx.x;
  const int wvid = t >> 6, l = t & 63, l16 = l & 15, g4 = l >> 4;
  const int brel = blockIdx.x >> 7;
  const int n0 = (blockIdx.x & 127) * 128;
  const int b = b0 + brel;

#pragma unroll
  for (int it = 0; it < 8; ++it) {
    int i = it * 512 + t;
    int c = i >> 5, j4 = i & 31;
    float4 xv = *(const float4*)(rep + (size_t)(b * 128 + c) * 16384 + n0 + j4 * 4);
    float vv[4] = {xv.x, xv.y, xv.z, xv.w};
#pragma unroll
    for (int r = 0; r < 4; ++r)
      *(unsigned short*)(XS + adr_q(j4 * 4 + r, c)) = f2b(vv[r]);
  }
  __syncthreads();

  k1_one(wb,         bq, qo, XS, WS, brel, n0, wvid, l, l16, g4);
  k1_one(wb + 16384, bk, ko, XS, WS, brel, n0, wvid, l, l16, g4);
  k1_one(wb + 32768, bv, vo, XS, WS, brel, n0, wvid, l, l16, g4);
}

// ================= K2: attention per (b,w), time-multiplexed S buffer =======
// 512 thr (8 waves), wave owns TWO 16-row m-tiles (hb0=wvid*32, hb1=+16).
// LDS: S 64K @0 (K during QK, then V^T during PV), PS 8x2K @64K. Total 80K
// -> 2 blocks/CU.  Compute bodies byte-equal to R16-validated versions.

__global__ __launch_bounds__(512, 2) void k2_attn(
    const unsigned short* __restrict__ qws, const unsigned short* __restrict__ kws,
    const unsigned short* __restrict__ vws, unsigned short* __restrict__ aws)
{
  extern __shared__ char smem[];
  char* S = smem;                                  // 64K shared K / V^T
  const int t = threadIdx.x;
  const int wvid = t >> 6, l = t & 63, l16 = l & 15, g4 = l >> 4;
  char* PS = smem + (64 << 10) + (wvid << 11);     // per-wave 2K

  const int brel = blockIdx.x >> 6;
  const int w = blockIdx.x & 63;
  const size_t wbase = (size_t)((brel * 64 + w)) * 256;   // row index of (b,w,h=0)

  const int hb0 = wvid * 32;
  const int hb1 = wvid * 32 + 16;

  // q rows for both m-tiles (contiguous reads)
  short8 qa0[4], qa1[4];
#pragma unroll
  for (int kk = 0; kk < 4; ++kk) {
    qa0[kk] = *(const short8*)(qws + (wbase + hb0 + l16) * 128 + kk * 32 + g4 * 8);
    qa1[kk] = *(const short8*)(qws + (wbase + hb1 + l16) * 128 + kk * 32 + g4 * 8);
  }

  // Phase 1: stage K rows [g][c] at permuted position p(g) into S
#pragma unroll
  for (int it = 0; it < 8; ++it) {
    int i = it * 512 + t;
    int g = i >> 4, c16 = i & 15;
    int gp = (g & ~31) | ((g & 4) << 2) | ((g >> 1) & 12) | (g & 3);
    short8 kv = *(const short8*)(kws + (wbase + g) * 128 + c16 * 8);
    *(short8*)(S + adr_s(gp, c16 * 8)) = kv;
  }
  __syncthreads();

  const float SCL2 = 0.08838834764831845f * 1.4426950408889634f; // rsqrt(128)*log2e

  // Phase 2: swapped scores, frag-reuse: each kb read feeds both m-tiles
  f32x4 sc0[16], sc1[16];
#pragma unroll
  for (int gt = 0; gt < 16; ++gt) {
    f32x4 a0 = {0.f, 0.f, 0.f, 0.f};
    f32x4 a1 = {0.f, 0.f, 0.f, 0.f};
#pragma unroll
    for (int kk = 0; kk < 4; ++kk) {
      short8 kb = ldsf(S, adr_s(gt * 16 + l16, kk * 32 + g4 * 8));
      MFMA16(a0, kb, qa0[kk]);
      MFMA16(a1, kb, qa1[kk]);
    }
    sc0[gt] = a0;
    sc1[gt] = a1;
  }
  __syncthreads();   // all waves finished reading K from S

  // Phase 3: stage V^T [c][g] into S (ds_writes retire under softmax VALU)
#pragma unroll
  for (int it = 0; it < 8; ++it) {
    int i = it * 512 + t;
    int g = i >> 4, c16 = i & 15;
    short8 vv = *(const short8*)(vws + (wbase + g) * 128 + c16 * 8);
#pragma unroll
    for (int j = 0; j < 8; ++j)
      *(unsigned short*)(S + adr_vt(c16 * 8 + j, g)) = (unsigned short)vv[j];
  }

  // softmax m0 (row h = hb0+l16): in-lane + 2 shfl; pack to pk (frees sc0)
  unsigned pk0a[16], pk1a[16];
  {
    float mm = fmaxf(fmaxf(sc0[0][0], sc0[0][1]), fmaxf(sc0[0][2], sc0[0][3]));
#pragma unroll
    for (int gt = 1; gt < 16; ++gt) {
      float m4 = fmaxf(fmaxf(sc0[gt][0], sc0[gt][1]), fmaxf(sc0[gt][2], sc0[gt][3]));
      mm = fmaxf(mm, m4);
    }
    mm = fmaxf(mm, __shfl_xor(mm, 16, 64));
    mm = fmaxf(mm, __shfl_xor(mm, 32, 64));
    const float mneg = -mm * SCL2;
    float s = 0.f;
#pragma unroll
    for (int gt = 0; gt < 16; ++gt) {
#pragma unroll
      for (int r = 0; r < 4; ++r) {
        float p = exp2f(fmaf(sc0[gt][r], SCL2, mneg));
        sc0[gt][r] = p;
        s += p;
      }
    }
    s += __shfl_xor(s, 16, 64);
    s += __shfl_xor(s, 32, 64);
    const float rcp = 1.0f / s;
#pragma unroll
    for (int gt = 0; gt < 16; ++gt) {
      pk0a[gt] = (unsigned)f2b(sc0[gt][0] * rcp) | ((unsigned)f2b(sc0[gt][1] * rcp) << 16);
      pk1a[gt] = (unsigned)f2b(sc0[gt][2] * rcp) | ((unsigned)f2b(sc0[gt][3] * rcp) << 16);
    }
  }
  // softmax m1
  unsigned pk0b[16], pk1b[16];
  {
    float mm = fmaxf(fmaxf(sc1[0][0], sc1[0][1]), fmaxf(sc1[0][2], sc1[0][3]));
#pragma unroll
    for (int gt = 1; gt < 16; ++gt) {
      float m4 = fmaxf(fmaxf(sc1[gt][0], sc1[gt][1]), fmaxf(sc1[gt][2], sc1[gt][3]));
      mm = fmaxf(mm, m4);
    }
    mm = fmaxf(mm, __shfl_xor(mm, 16, 64));
    mm = fmaxf(mm, __shfl_xor(mm, 32, 64));
    const float mneg = -mm * SCL2;
    float s = 0.f;
#pragma unroll
    for (int gt = 0; gt < 16; ++gt) {
#pragma unroll
      for (int r = 0; r < 4; ++r) {
        float p = exp2f(fmaf(sc1[gt][r], SCL2, mneg));
        sc1[gt][r] = p;
        s += p;
      }
    }
    s += __shfl_xor(s, 16, 64);
    s += __shfl_xor(s, 32, 64);
    const float rcp = 1.0f / s;
#pragma unroll
    for (int gt = 0; gt < 16; ++gt) {
      pk0b[gt] = (unsigned)f2b(sc1[gt][0] * rcp) | ((unsigned)f2b(sc1[gt][1] * rcp) << 16);
      pk1b[gt] = (unsigned)f2b(sc1[gt][2] * rcp) | ((unsigned)f2b(sc1[gt][3] * rcp) << 16);
    }
  }
  __syncthreads();   // V^T fully staged in S

  // Phase 4: PV, frag-reuse: each vb read feeds both m-tiles (lane-local A-frags)
  f32x4 oacc0[8], oacc1[8];
#pragma unroll
  for (int nt = 0; nt < 8; ++nt) {
    oacc0[nt] = (f32x4){0.f, 0.f, 0.f, 0.f};
    oacc1[nt] = (f32x4){0.f, 0.f, 0.f, 0.f};
  }
#pragma unroll
  for (int kks = 0; kks < 8; ++kks) {
    int4v pv0 = {(int)pk0a[2 * kks], (int)pk1a[2 * kks],
                 (int)pk0a[2 * kks + 1], (int)pk1a[2 * kks + 1]};
    int4v pv1 = {(int)pk0b[2 * kks], (int)pk1b[2 * kks],
                 (int)pk0b[2 * kks + 1], (int)pk1b[2 * kks + 1]};
    short8 pa0 = __builtin_bit_cast(short8, pv0);
    short8 pa1 = __builtin_bit_cast(short8, pv1);
#pragma unroll
    for (int nt = 0; nt < 8; ++nt) {
      short8 vb = ldsf(S, adr_vt(nt * 16 + l16, kks * 32 + g4 * 8));
      MFMA16(oacc0[nt], pa0, vb);
      MFMA16(oacc1[nt], pa1, vb);
    }
  }

  // att stores (normalized), R14-validated PS round-trip, once per m-tile
#pragma unroll
  for (int m = 0; m < 2; ++m) {
    const int hb = (m == 0) ? hb0 : hb1;
#pragma unroll
    for (int ch = 0; ch < 2; ++ch) {
#pragma unroll
      for (int nt4 = 0; nt4 < 4; ++nt4) {
        int nt = ch * 4 + nt4;
        f32x4 ov = (m == 0) ? oacc0[nt] : oacc1[nt];
#pragma unroll
        for (int r = 0; r < 4; ++r)
          *(unsigned short*)(PS + ps_adr(g4 * 4 + r, nt4 * 16 + l16)) = f2b(ov[r]);
      }
#pragma unroll
      for (int it = 0; it < 8; ++it) {
        int row = it * 2 + (l >> 5);   // 0..15
        int cd  = l & 31;              // dword within 128B row-half
        unsigned base = (unsigned)(row << 7) +
            (((unsigned)(cd << 2)) ^ (((unsigned)((row ^ (row >> 3)) & 7)) << 4));
        unsigned lo = *(const unsigned short*)(PS + base);
        unsigned hi = *(const unsigned short*)(PS + base + 2);
        ((unsigned*)aws)[(wbase + hb + row) * 64 + ch * 32 + cd] = lo | (hi << 16);
      }
    }
  }
}

// ================= K3: out = relu(wfc . att^T + bfc) — R8-validated ==========
// grid = nbc*64; block tile = 256 n.  LDS: AS [256n][128c] (64K).

__global__ __launch_bounds__(512, 4) void k3_conv(
    const unsigned short* __restrict__ aws, const unsigned short* __restrict__ wb,
    const float* __restrict__ bfc, float* __restrict__ out, int b0)
{
  extern __shared__ char smem[];
  char* AS = smem;

  const int t = threadIdx.x;
  const int wvid = t >> 6, l = t & 63, l16 = l & 15, g4 = l >> 4;
  (void)l;
  const int brel = blockIdx.x >> 6;
  const int n0 = (blockIdx.x & 63) * 256;
  const int b = b0 + brel;

#pragma unroll
  for (int it = 0; it < 8; ++it) {
    int i = it * 512 + t;
    int nn = i >> 4, c16 = i & 15;
    int n = n0 + nn;
    int h = n >> 6, w = n & 63;
    short8 av = *(const short8*)(aws + ((size_t)((brel * 64 + w) * 256 + h)) * 128 + c16 * 8);
    *(short8*)(AS + adr_s(nn, c16 * 8)) = av;
  }
  __syncthreads();

  const int strip = wvid * 16;
  const unsigned short* wfcb = wb + 3 * 16384;
  short8 wf[4];
#pragma unroll
  for (int kk = 0; kk < 4; ++kk)
    wf[kk] = *(const short8*)(wfcb + (strip + l16) * 128 + kk * 32 + g4 * 8);
  float bv4[4];
#pragma unroll
  for (int r = 0; r < 4; ++r) bv4[r] = bfc[strip + g4 * 4 + r];

#pragma unroll
  for (int nt = 0; nt < 16; ++nt) {
    f32x4 acc = {0.f, 0.f, 0.f, 0.f};
#pragma unroll
    for (int kk = 0; kk < 4; ++kk) {
      short8 ab = ldsf(AS, adr_s(nt * 16 + l16, kk * 32 + g4 * 8));
      MFMA16(acc, wf[kk], ab);
    }
#pragma unroll
    for (int r = 0; r < 4; ++r) {
      int o = strip + g4 * 4 + r;
      out[(size_t)(b * 128 + o) * 16384 + n0 + nt * 16 + l16] = fmaxf(acc[r] + bv4[r], 0.f);
    }
  }
}

extern "C" void kernel_launch(void* const* d_in, const int* in_sizes, int n_in,
                              void* d_out, int out_size, void* d_ws, size_t ws_size,
                              hipStream_t stream) {
  const float* rep = (const float*)d_in[0];
  const float* wq  = (const float*)d_in[1];
  const float* bq  = (const float*)d_in[2];
  const float* wk  = (const float*)d_in[3];
  const float* bk  = (const float*)d_in[4];
  const float* wv  = (const float*)d_in[5];
  const float* bv  = (const float*)d_in[6];
  const float* wfc = (const float*)d_in[7];
  const float* bfc = (const float*)d_in[8];
  float* out = (float*)d_out;
  (void)in_sizes; (void)n_in; (void)out_size;

  hipFuncSetAttribute((const void*)k1_qkv,  hipFuncAttributeMaxDynamicSharedMemorySize, 40 * 1024);
  hipFuncSetAttribute((const void*)k2_attn, hipFuncAttributeMaxDynamicSharedMemorySize, 80 * 1024);
  hipFuncSetAttribute((const void*)k3_conv, hipFuncAttributeMaxDynamicSharedMemorySize, 64 * 1024);

  const size_t wb_bytes = 4 * 16384 * 2;          // 128 KB bf16 weights
  const size_t per_b = (size_t)16384 * 128 * 2;   // 4 MiB per array per b
  if (ws_size < wb_bytes + 4 * per_b) return;     // needs >= ~16.1 MB
  size_t nb_max = (ws_size - wb_bytes) / (4 * per_b);
  int nb = (int)(nb_max < 16 ? nb_max : 16);

  char* ws = (char*)d_ws;
  unsigned short* qws = (unsigned short*)(ws);
  unsigned short* kws = (unsigned short*)(ws + (size_t)nb * per_b);
  unsigned short* vws = (unsigned short*)(ws + (size_t)nb * per_b * 2);
  unsigned short* aws = (unsigned short*)(ws + (size_t)nb * per_b * 3);
  unsigned short* wb  = (unsigned short*)(ws + (size_t)nb * per_b * 4);

  k0_wcvt<<<dim3(64), dim3(256), 0, stream>>>(wq, wk, wv, wfc, wb);

  for (int b0 = 0; b0 < 16; b0 += nb) {
    int nbc = (16 - b0) < nb ? (16 - b0) : nb;
    k1_qkv<<<dim3(nbc * 128), dim3(512), 40 * 1024, stream>>>(
        rep, wb, bq, bk, bv, qws, kws, vws, b0);
    k2_attn<<<dim3(nbc * 64), dim3(512), 80 * 1024, stream>>>(qws, kws, vws, aws);
    k3_conv<<<dim3(nbc * 64), dim3(512), 64 * 1024, stream>>>(aws, wb, bfc, out, b0);
  }
}